// Round 1
// baseline (272.369 us; speedup 1.0000x reference)
//
#include <hip/hip_runtime.h>

#define EPS_F 1e-6f
#define LOG2E 1.4426950408889634f

// Force a (known-uniform) float into an SGPR.
__device__ __forceinline__ float rfl(float x) {
    return __builtin_bit_cast(float, __builtin_amdgcn_readfirstlane(__builtin_bit_cast(int, x)));
}

// Grid: 1024 blocks = B(8) * m-tiles(4) * n-chunks(32); block = 256 threads.
// Thread owns one output row m (all 15 (k,c) accumulators), sums a 32-long n chunk,
// then atomically adds into d_out (zeroed via hipMemsetAsync before launch).
__global__ __launch_bounds__(256, 4) void icgp_rbf_kernel(
    const float* __restrict__ xa,       // (B, N1, 1, 3)
    const float* __restrict__ feat,     // (B, N1, 5, 3)
    const float* __restrict__ xt,       // (B, N2, 1, 3)
    const float* __restrict__ log_std,  // (1, 5, 3)
    float* __restrict__ out)            // (B, N2, 5, 3)
{
    const int NC = 32;            // n-chunks
    const int CHUNK = 1024 / NC;  // 32 n's per block

    const int bid = blockIdx.x;
    const int nc = bid & (NC - 1);
    const int mt = (bid >> 5) & 3;
    const int b  = bid >> 7;
    const int m  = mt * 256 + threadIdx.x;

    // Per-(k,c) coefficient: wt = exp2(coef * (xa-xt)^2), coef = -0.5*log2(e)/std^2.
    // Values are wave-uniform (uniform loads) -> pin to SGPRs.
    float coef[15];
    #pragma unroll
    for (int kc = 0; kc < 15; ++kc) {
        float s = __expf(log_std[kc]) + EPS_F;
        coef[kc] = rfl(-0.5f * LOG2E / (s * s));
    }

    // Runtime check: are all K coefficients identical per channel?
    bool uni = true;
    #pragma unroll
    for (int k = 1; k < 5; ++k)
        #pragma unroll
        for (int c = 0; c < 3; ++c)
            uni = uni && (coef[k * 3 + c] == coef[c]);

    // Per-thread target point (3 VGPRs).
    const float t0 = xt[(b * 1024 + m) * 3 + 0];
    const float t1 = xt[(b * 1024 + m) * 3 + 1];
    const float t2 = xt[(b * 1024 + m) * 3 + 2];

    const float* __restrict__ xab = xa   + (size_t)b * 1024 * 3;
    const float* __restrict__ fb  = feat + (size_t)b * 1024 * 15;
    const int n0 = nc * CHUNK;

    float acc[15];
    #pragma unroll
    for (int kc = 0; kc < 15; ++kc) acc[kc] = 0.0f;

    if (uni) {
        // Fast path: weight depends only on channel c -> 3 exps per n.
        const float c0 = coef[0], c1 = coef[1], c2 = coef[2];
        #pragma unroll 2
        for (int n = n0; n < n0 + CHUNK; ++n) {
            const float a0 = xab[n * 3 + 0];
            const float a1 = xab[n * 3 + 1];
            const float a2 = xab[n * 3 + 2];
            float d0 = a0 - t0; d0 *= d0;
            float d1 = a1 - t1; d1 *= d1;
            float d2 = a2 - t2; d2 *= d2;
            const float w0 = __builtin_amdgcn_exp2f(d0 * c0);
            const float w1 = __builtin_amdgcn_exp2f(d1 * c1);
            const float w2 = __builtin_amdgcn_exp2f(d2 * c2);
            const float* __restrict__ f = fb + n * 15;
            #pragma unroll
            for (int k = 0; k < 5; ++k) {
                acc[k * 3 + 0] += w0 * f[k * 3 + 0];
                acc[k * 3 + 1] += w1 * f[k * 3 + 1];
                acc[k * 3 + 2] += w2 * f[k * 3 + 2];
            }
        }
    } else {
        // General path: 15 exps per n.
        for (int n = n0; n < n0 + CHUNK; ++n) {
            const float a0 = xab[n * 3 + 0];
            const float a1 = xab[n * 3 + 1];
            const float a2 = xab[n * 3 + 2];
            float dd[3];
            dd[0] = a0 - t0; dd[0] *= dd[0];
            dd[1] = a1 - t1; dd[1] *= dd[1];
            dd[2] = a2 - t2; dd[2] *= dd[2];
            const float* __restrict__ f = fb + n * 15;
            #pragma unroll
            for (int k = 0; k < 5; ++k)
                #pragma unroll
                for (int c = 0; c < 3; ++c)
                    acc[k * 3 + c] +=
                        __builtin_amdgcn_exp2f(dd[c] * coef[k * 3 + c]) * f[k * 3 + c];
        }
    }

    float* __restrict__ ob = out + ((size_t)b * 1024 + m) * 15;
    #pragma unroll
    for (int kc = 0; kc < 15; ++kc)
        atomicAdd(ob + kc, acc[kc]);
}

extern "C" void kernel_launch(void* const* d_in, const int* in_sizes, int n_in,
                              void* d_out, int out_size, void* d_ws, size_t ws_size,
                              hipStream_t stream) {
    const float* xa      = (const float*)d_in[0];  // (8,1024,1,3)
    const float* feat    = (const float*)d_in[1];  // (8,1024,5,3)
    const float* xt      = (const float*)d_in[2];  // (8,1024,1,3)
    const float* log_std = (const float*)d_in[3];  // (1,5,3)
    float* out = (float*)d_out;                    // (8,1024,5,3)

    hipMemsetAsync(out, 0, (size_t)out_size * sizeof(float), stream);
    icgp_rbf_kernel<<<dim3(1024), dim3(256), 0, stream>>>(xa, feat, xt, log_std, out);
}

// Round 2
// 92.746 us; speedup vs baseline: 2.9367x; 2.9367x over previous
//
#include <hip/hip_runtime.h>

#define EPS_F 1e-6f
#define LOG2E 1.4426950408889634f

// Force a (known-uniform) float into an SGPR.
__device__ __forceinline__ float rfl(float x) {
    return __builtin_bit_cast(float, __builtin_amdgcn_readfirstlane(__builtin_bit_cast(int, x)));
}

// Block: 256 threads = 8 m (mi = tid>>5) x 32 n-splits (ns = tid&31).
// Grid: 1024 blocks = B(8) x 128 m-tiles. Each thread accumulates 15 (k,c)
// sums over its 32 interleaved n's (n = i*32+ns -> lane-consecutive loads),
// partials combined in LDS, one plain store per output element. No atomics.
__global__ __launch_bounds__(256, 4) void icgp_rbf_kernel(
    const float* __restrict__ xa,       // (B, N1, 1, 3)
    const float* __restrict__ feat,     // (B, N1, 5, 3)
    const float* __restrict__ xt,       // (B, N2, 1, 3)
    const float* __restrict__ log_std,  // (1, 5, 3)
    float* __restrict__ out)            // (B, N2, 5, 3)
{
    __shared__ float lds[256 * 15];     // 15 KB partials

    const int bid = blockIdx.x;
    const int mt  = bid & 127;          // m-tile index (8 m's per tile)
    const int b   = bid >> 7;
    const int tid = threadIdx.x;
    const int mi  = tid >> 5;           // 0..7
    const int ns  = tid & 31;           // 0..31
    const int m   = mt * 8 + mi;

    // wt = exp2(coef * (xa-xt)^2), coef = -0.5*log2(e)/std^2 ; wave-uniform -> SGPR.
    float coef[15];
    #pragma unroll
    for (int kc = 0; kc < 15; ++kc) {
        float s = __expf(log_std[kc]) + EPS_F;
        coef[kc] = rfl(-0.5f * LOG2E / (s * s));
    }

    // Runtime check: all K coefficients identical per channel? (true for given params)
    bool uni = true;
    #pragma unroll
    for (int k = 1; k < 5; ++k)
        #pragma unroll
        for (int c = 0; c < 3; ++c)
            uni = uni && (coef[k * 3 + c] == coef[c]);

    const float t0 = xt[(b * 1024 + m) * 3 + 0];
    const float t1 = xt[(b * 1024 + m) * 3 + 1];
    const float t2 = xt[(b * 1024 + m) * 3 + 2];

    const float* __restrict__ xab = xa   + (size_t)b * 1024 * 3;
    const float* __restrict__ fb  = feat + (size_t)b * 1024 * 15;

    float acc[15];
    #pragma unroll
    for (int kc = 0; kc < 15; ++kc) acc[kc] = 0.0f;

    if (uni) {
        const float c0 = coef[0], c1 = coef[1], c2 = coef[2];
        #pragma unroll 4
        for (int i = 0; i < 32; ++i) {
            const int n = i * 32 + ns;              // lane-consecutive n
            const float a0 = xab[n * 3 + 0];
            const float a1 = xab[n * 3 + 1];
            const float a2 = xab[n * 3 + 2];
            float d0 = a0 - t0; d0 *= d0;
            float d1 = a1 - t1; d1 *= d1;
            float d2 = a2 - t2; d2 *= d2;
            const float w0 = __builtin_amdgcn_exp2f(d0 * c0);
            const float w1 = __builtin_amdgcn_exp2f(d1 * c1);
            const float w2 = __builtin_amdgcn_exp2f(d2 * c2);
            const float* __restrict__ f = fb + n * 15;
            #pragma unroll
            for (int k = 0; k < 5; ++k) {
                acc[k * 3 + 0] += w0 * f[k * 3 + 0];
                acc[k * 3 + 1] += w1 * f[k * 3 + 1];
                acc[k * 3 + 2] += w2 * f[k * 3 + 2];
            }
        }
    } else {
        // General path: 15 exps per n (correct for arbitrary log_std).
        for (int i = 0; i < 32; ++i) {
            const int n = i * 32 + ns;
            const float a0 = xab[n * 3 + 0];
            const float a1 = xab[n * 3 + 1];
            const float a2 = xab[n * 3 + 2];
            float dd[3];
            dd[0] = a0 - t0; dd[0] *= dd[0];
            dd[1] = a1 - t1; dd[1] *= dd[1];
            dd[2] = a2 - t2; dd[2] *= dd[2];
            const float* __restrict__ f = fb + n * 15;
            #pragma unroll
            for (int k = 0; k < 5; ++k)
                #pragma unroll
                for (int c = 0; c < 3; ++c)
                    acc[k * 3 + c] +=
                        __builtin_amdgcn_exp2f(dd[c] * coef[k * 3 + c]) * f[k * 3 + c];
        }
    }

    // Stash partials: layout [mi][ns][15] (tid = mi*32+ns).
    #pragma unroll
    for (int kc = 0; kc < 15; ++kc) lds[tid * 15 + kc] = acc[kc];
    __syncthreads();

    // 120 outputs per block (8 m x 15 kc); thread t sums 32 ns-partials.
    if (tid < 120) {
        const int mi2 = tid / 15;
        const int kc  = tid - mi2 * 15;
        float s = 0.0f;
        #pragma unroll
        for (int ns2 = 0; ns2 < 32; ++ns2)
            s += lds[(mi2 * 32 + ns2) * 15 + kc];
        out[((size_t)b * 1024 + mt * 8 + mi2) * 15 + kc] = s;
    }
}

extern "C" void kernel_launch(void* const* d_in, const int* in_sizes, int n_in,
                              void* d_out, int out_size, void* d_ws, size_t ws_size,
                              hipStream_t stream) {
    const float* xa      = (const float*)d_in[0];  // (8,1024,1,3)
    const float* feat    = (const float*)d_in[1];  // (8,1024,5,3)
    const float* xt      = (const float*)d_in[2];  // (8,1024,1,3)
    const float* log_std = (const float*)d_in[3];  // (1,5,3)
    float* out = (float*)d_out;                    // (8,1024,5,3)

    icgp_rbf_kernel<<<dim3(1024), dim3(256), 0, stream>>>(xa, feat, xt, log_std, out);
}